// Round 7
// baseline (1103.103 us; speedup 1.0000x reference)
//
#include <hip/hip_runtime.h>
#include <hip/hip_bf16.h>

// Problem dims (fixed by setup_inputs)
constexpr int B = 4, H = 8, N = 4096, E = 64, D = 512;   // d_model = H*E = 512
constexpr int BH = B * H;          // 32
constexpr int CHUNK = 32;          // positions per chunk
constexpr int NCH = N / CHUNK;     // 128 chunks per (b,h)
constexpr int NTILES = BH * NCH;   // 4096
constexpr float EPS = 1e-5f;
constexpr int TM = 128, TN = 128, BK = 64;   // GEMM tiling (proven R3)

typedef __attribute__((ext_vector_type(4))) float floatx4;
typedef __attribute__((ext_vector_type(8))) short short8;

__device__ __forceinline__ float phi(float x) {
    return (x > 0.0f) ? (x + 1.0f) : __expf(x);   // elu(x) + 1
}

// ---------------------------------------------------------------------------
// Single-pass scan with decoupled lookback.
// grid: 1024 blocks x 256 threads; each block FCFS-grabs 4 consecutive chunk
// tiles (atomic counter) -> tile order == schedule order -> deadlock-free.
// Per wave (one 32-position chunk, lane = dim e):
//   1. load k,v; local inclusive cumsums in registers; chunk totals
//   2. publish aggregate (flag 1) via device-scope atomics
//   3. lookback over predecessors (stop at flag 2 = inclusive), accumulate
//   4. publish inclusive (flag 2)
//   5. load q, butterfly dot products, write bf16 attn [b,n,h*e]
// W -> bf16 folded in (1024*256 threads == 512*512 elements).
// ---------------------------------------------------------------------------
__global__ __launch_bounds__(256) void scan_lookback(
        const float* __restrict__ q, const float* __restrict__ k,
        const float* __restrict__ v, const float* __restrict__ W,
        __hip_bfloat16* __restrict__ wb,
        float* __restrict__ agg, float* __restrict__ incl,
        int* __restrict__ flags, int* __restrict__ counter,
        __hip_bfloat16* __restrict__ attn) {
    const int tid = threadIdx.x;

    // W convert: exactly one element per thread
    {
        int gid = blockIdx.x * 256 + tid;
        wb[gid] = __float2bfloat16(W[gid]);
    }

    __shared__ int tb;
    if (tid == 0) tb = atomicAdd(counter, 4);
    __syncthreads();
    const int w = tid >> 6, lane = tid & 63;
    const int tile = tb + w;                 // 0..4095
    const int bh = tile >> 7, ch = tile & 127;
    const int b_ = bh >> 3, h_ = bh & 7;

    const size_t gbase = ((size_t)bh * N + (size_t)ch * CHUNK) * E + lane;
    const float* kp = k + gbase;
    const float* vp = v + gbase;
    const float* qp = q + gbase;

    // ---- 1. local scan (registers) ----
    float kcl[CHUNK], vcl[CHUNK];
    float kc = 0.f, vc = 0.f;
    #pragma unroll
    for (int g = 0; g < 4; g++) {
        float kb[8], vb[8];
        #pragma unroll
        for (int j = 0; j < 8; j++) {
            size_t o = (size_t)(g * 8 + j) * E;
            kb[j] = kp[o]; vb[j] = vp[o];
        }
        #pragma unroll
        for (int j = 0; j < 8; j++) {
            kc += phi(kb[j]);
            vc += vb[j];
            kcl[g * 8 + j] = kc;
            vcl[g * 8 + j] = vc;
        }
    }

    float koff = 0.f, voff = 0.f;
    if (ch == 0) {
        // inclusive == aggregate; publish flag 2 directly
        __hip_atomic_store(&incl[(size_t)tile * 128 + lane], kc,
                           __ATOMIC_RELAXED, __HIP_MEMORY_SCOPE_AGENT);
        __hip_atomic_store(&incl[(size_t)tile * 128 + 64 + lane], vc,
                           __ATOMIC_RELAXED, __HIP_MEMORY_SCOPE_AGENT);
        __threadfence();
        if (lane == 0)
            __hip_atomic_store(&flags[tile], 2, __ATOMIC_RELEASE, __HIP_MEMORY_SCOPE_AGENT);
    } else {
        // ---- 2. publish aggregate ----
        __hip_atomic_store(&agg[(size_t)tile * 128 + lane], kc,
                           __ATOMIC_RELAXED, __HIP_MEMORY_SCOPE_AGENT);
        __hip_atomic_store(&agg[(size_t)tile * 128 + 64 + lane], vc,
                           __ATOMIC_RELAXED, __HIP_MEMORY_SCOPE_AGENT);
        __threadfence();
        if (lane == 0)
            __hip_atomic_store(&flags[tile], 1, __ATOMIC_RELEASE, __HIP_MEMORY_SCOPE_AGENT);
        // ---- 3. lookback ----
        int t = tile - 1;
        while (true) {
            int f = __hip_atomic_load(&flags[t], __ATOMIC_ACQUIRE, __HIP_MEMORY_SCOPE_AGENT);
            if (f == 0) { __builtin_amdgcn_s_sleep(1); continue; }
            if (f == 2) {
                koff += __hip_atomic_load(&incl[(size_t)t * 128 + lane],
                                          __ATOMIC_RELAXED, __HIP_MEMORY_SCOPE_AGENT);
                voff += __hip_atomic_load(&incl[(size_t)t * 128 + 64 + lane],
                                          __ATOMIC_RELAXED, __HIP_MEMORY_SCOPE_AGENT);
                break;
            }
            // f == 1: add aggregate, continue back (a ch==0 tile always has flag 2,
            // so t-1 stays within this bh)
            koff += __hip_atomic_load(&agg[(size_t)t * 128 + lane],
                                      __ATOMIC_RELAXED, __HIP_MEMORY_SCOPE_AGENT);
            voff += __hip_atomic_load(&agg[(size_t)t * 128 + 64 + lane],
                                      __ATOMIC_RELAXED, __HIP_MEMORY_SCOPE_AGENT);
            t--;
        }
        // ---- 4. publish inclusive ----
        __hip_atomic_store(&incl[(size_t)tile * 128 + lane], koff + kc,
                           __ATOMIC_RELAXED, __HIP_MEMORY_SCOPE_AGENT);
        __hip_atomic_store(&incl[(size_t)tile * 128 + 64 + lane], voff + vc,
                           __ATOMIC_RELAXED, __HIP_MEMORY_SCOPE_AGENT);
        __threadfence();
        if (lane == 0)
            __hip_atomic_store(&flags[tile], 2, __ATOMIC_RELEASE, __HIP_MEMORY_SCOPE_AGENT);
    }

    // ---- 5. attn compute + store (proven R3/R6 code path) ----
    __hip_bfloat16* op = attn + ((size_t)(b_ * N + ch * CHUNK)) * D + h_ * E + lane;
    #pragma unroll
    for (int g = 0; g < 4; g++) {
        float qb[8], pr[8];
        #pragma unroll
        for (int j = 0; j < 8; j++) qb[j] = qp[(size_t)(g * 8 + j) * E];
        #pragma unroll
        for (int j = 0; j < 8; j++) pr[j] = phi(qb[j]) * (koff + kcl[g * 8 + j]);
        #pragma unroll
        for (int m = 1; m < 64; m <<= 1) {
            #pragma unroll
            for (int j = 0; j < 8; j++) pr[j] += __shfl_xor(pr[j], m, 64);
        }
        #pragma unroll
        for (int j = 0; j < 8; j++) {
            float s = pr[j];
            op[(size_t)(g * 8 + j) * D] =
                __float2bfloat16(s / (s + EPS) * (voff + vcl[g * 8 + j]));
        }
    }
}

// ---------------------------------------------------------------------------
// GEMM: out[16384,512] = attn_bf16 @ wb^T + bias (fp32). Proven R3 kernel:
// 128x128 tile, 4 waves, BK=64, global_load_lds width-16, XOR-swizzled LDS.
// ---------------------------------------------------------------------------
__global__ __launch_bounds__(256, 2) void gemm_bf16(
        const __hip_bfloat16* __restrict__ A,
        const __hip_bfloat16* __restrict__ Bw,
        const float* __restrict__ bias,
        float* __restrict__ out) {
    __shared__ short Alds[TM * BK];
    __shared__ short Blds[TN * BK];
    int tile = blockIdx.x;
    int tm = tile >> 2, tn = tile & 3;
    int tid = threadIdx.x;
    int w = tid >> 6;
    int lane = tid & 63;
    int lo = lane & 15, quad = lane >> 4;
    int wm = w & 1, wn = w >> 1;
    int srow = lane >> 3;
    int cgp = lane & 7;

    floatx4 acc[4][4] = {};
    const short* Ag = (const short*)A;
    const short* Bg = (const short*)Bw;

    for (int k0 = 0; k0 < D; k0 += BK) {
        __syncthreads();
        #pragma unroll
        for (int t = 0; t < 4; t++) {
            int r = w * 32 + t * 8 + srow;
            int gg = cgp ^ srow;
            const short* ga = Ag + (size_t)(tm * TM + r) * D + k0 + gg * 8;
            const short* gb = Bg + (size_t)(tn * TN + r) * D + k0 + gg * 8;
            __builtin_amdgcn_global_load_lds(
                (const __attribute__((address_space(1))) void*)ga,
                (__attribute__((address_space(3))) void*)&Alds[(w * 32 + t * 8) * BK],
                16, 0, 0);
            __builtin_amdgcn_global_load_lds(
                (const __attribute__((address_space(1))) void*)gb,
                (__attribute__((address_space(3))) void*)&Blds[(w * 32 + t * 8) * BK],
                16, 0, 0);
        }
        __syncthreads();
        #pragma unroll
        for (int kk = 0; kk < 2; kk++) {
            short8 af[4], bfr[4];
            #pragma unroll
            for (int i = 0; i < 4; i++) {
                int ra = wm * 64 + i * 16 + lo;
                af[i] = *(const short8*)&Alds[ra * BK + (((kk << 2) | quad) ^ (lo & 7)) * 8];
                int rb = wn * 64 + i * 16 + lo;
                bfr[i] = *(const short8*)&Blds[rb * BK + (((kk << 2) | quad) ^ (lo & 7)) * 8];
            }
            #pragma unroll
            for (int i = 0; i < 4; i++)
                #pragma unroll
                for (int j = 0; j < 4; j++)
                    acc[i][j] = __builtin_amdgcn_mfma_f32_16x16x32_bf16(af[i], bfr[j], acc[i][j], 0, 0, 0);
        }
    }

    #pragma unroll
    for (int i = 0; i < 4; i++) {
        #pragma unroll
        for (int j = 0; j < 4; j++) {
            int n = tn * TN + wn * 64 + j * 16 + lo;
            float bv = bias[n];
            #pragma unroll
            for (int r = 0; r < 4; r++) {
                int m = tm * TM + wm * 64 + i * 16 + quad * 4 + r;
                out[(size_t)m * D + n] = acc[i][j][r] + bv;
            }
        }
    }
}

// ---------------------------------------------------------------------------

extern "C" void kernel_launch(void* const* d_in, const int* in_sizes, int n_in,
                              void* d_out, int out_size, void* d_ws, size_t ws_size,
                              hipStream_t stream) {
    const float* q   = (const float*)d_in[0];
    const float* k   = (const float*)d_in[1];
    const float* v   = (const float*)d_in[2];
    // d_in[3] = mask (unused)
    const float* W   = (const float*)d_in[4];
    const float* bfc = (const float*)d_in[5];
    float* out = (float*)d_out;

    char* ws = (char*)d_ws;
    __hip_bfloat16* attn = (__hip_bfloat16*)ws;                         // 16 MiB
    __hip_bfloat16* wb   = (__hip_bfloat16*)(ws + (16 << 20));          // 512 KiB
    float* agg   = (float*)(ws + (16 << 20) + (512 << 10));             // 2 MiB
    float* incl  = agg + (size_t)NTILES * 128;                          // 2 MiB
    int*   flags = (int*)(incl + (size_t)NTILES * 128);                 // 16 KiB
    int*   counter = flags + NTILES;                                    // 4 B

    // zero flags + counter (re-poisoned to 0xAA before every timed launch)
    hipMemsetAsync(flags, 0, (NTILES + 1) * sizeof(int), stream);

    hipLaunchKernelGGL(scan_lookback, dim3(1024), dim3(256), 0, stream,
                       q, k, v, W, wb, agg, incl, flags, counter, attn);
    hipLaunchKernelGGL(gemm_bf16, dim3((B * N / TM) * (D / TN)), dim3(256), 0, stream,
                       attn, wb, bfc, out);
}

// Round 8
// 176.194 us; speedup vs baseline: 6.2607x; 6.2607x over previous
//
#include <hip/hip_runtime.h>
#include <hip/hip_bf16.h>

// Problem dims (fixed by setup_inputs)
constexpr int B = 4, H = 8, N = 4096, E = 64, D = 512;   // d_model = H*E = 512
constexpr int BH = B * H;          // 32
constexpr int CHUNK = 32;          // positions per chunk
constexpr int NCH = N / CHUNK;     // 128 chunks per (b,h)
constexpr float EPS = 1e-5f;

typedef __attribute__((ext_vector_type(4))) float floatx4;
typedef __attribute__((ext_vector_type(8))) short short8;

__device__ __forceinline__ float phi(float x) {
    return (x > 0.0f) ? (x + 1.0f) : __expf(x);   // elu(x) + 1
}

// ---------------------------------------------------------------------------
// Kernel 1 (proven R6): per-(bh,chunk) sums of phi(k), v, transposed out
// ksumT[bh*64+e][ch]; W -> bf16 folded in (grid is exactly 512*512 threads).
// grid: 1024 blocks x 256 threads, one wave per 32-chunk.
// ---------------------------------------------------------------------------
__global__ void chunk_sums(const float* __restrict__ k, const float* __restrict__ v,
                           const float* __restrict__ W, __hip_bfloat16* __restrict__ wb,
                           float* __restrict__ ksumT, float* __restrict__ vsumT) {
    int gid = blockIdx.x * 256 + threadIdx.x;
    wb[gid] = __float2bfloat16(W[gid]);

    int wave = (blockIdx.x << 2) | (threadIdx.x >> 6);   // chunk id 0..4095
    int lane = threadIdx.x & 63;
    int bh = wave >> 7, ch = wave & 127;
    int qd = lane >> 4;          // row-phase 0..3
    int c  = lane & 15;          // col-group (4 dims)
    const float* kp = k + ((size_t)bh * N + (size_t)ch * CHUNK) * E;
    const float* vp = v + ((size_t)bh * N + (size_t)ch * CHUNK) * E;
    floatx4 ks = {0.f, 0.f, 0.f, 0.f}, vs = {0.f, 0.f, 0.f, 0.f};
    #pragma unroll
    for (int i = 0; i < CHUNK / 4; i++) {
        int off = (i * 4 + qd) * E + c * 4;
        floatx4 kv = *(const floatx4*)(kp + off);
        floatx4 vv = *(const floatx4*)(vp + off);
        #pragma unroll
        for (int j = 0; j < 4; j++) ks[j] += phi(kv[j]);
        vs += vv;
    }
    #pragma unroll
    for (int j = 0; j < 4; j++) {
        ks[j] += __shfl_xor(ks[j], 16, 64);
        ks[j] += __shfl_xor(ks[j], 32, 64);
        vs[j] += __shfl_xor(vs[j], 16, 64);
        vs[j] += __shfl_xor(vs[j], 32, 64);
    }
    int d = c * 4 + qd;
    ksumT[(size_t)(bh * E + d) * NCH + ch] = ks[qd];
    vsumT[(size_t)(bh * E + d) * NCH + ch] = vs[qd];
}

// ---------------------------------------------------------------------------
// Kernel 2 (proven R3): exclusive prefix over 128 chunks per (bh,e).
// ---------------------------------------------------------------------------
__global__ void chunk_prefix(float* __restrict__ ksumT, float* __restrict__ vsumT) {
    int wid = (blockIdx.x << 2) | (threadIdx.x >> 6);   // bh*64+e, 0..2047
    int lane = threadIdx.x & 63;
    size_t base = (size_t)wid * NCH;
    float x0 = ksumT[base + lane],      y0 = vsumT[base + lane];
    float x1 = ksumT[base + 64 + lane], y1 = vsumT[base + 64 + lane];
    float ox0 = x0, oy0 = y0, ox1 = x1, oy1 = y1;
    #pragma unroll
    for (int dlt = 1; dlt < 64; dlt <<= 1) {
        float t0 = __shfl_up(x0, dlt, 64);
        float u0 = __shfl_up(y0, dlt, 64);
        float t1 = __shfl_up(x1, dlt, 64);
        float u1 = __shfl_up(y1, dlt, 64);
        if (lane >= dlt) { x0 += t0; y0 += u0; x1 += t1; y1 += u1; }
    }
    float tx = __shfl(x0, 63, 64);
    float ty = __shfl(y0, 63, 64);
    ksumT[base + lane]      = x0 - ox0;
    vsumT[base + lane]      = y0 - oy0;
    ksumT[base + 64 + lane] = x1 - ox1 + tx;
    vsumT[base + 64 + lane] = y1 - oy1 + ty;
}

// ---------------------------------------------------------------------------
// Kernel 3: fused scan + output matmul, NO recompute, NO attn in HBM.
// Block = (batch, chunk of 32 positions), 512 threads = 8 waves = 8 heads.
// Each wave: proven scan math for its head's 64 dims -> bf16 attn slice
// [32 x 64] into LDS (R6's proven XOR colgrp swizzle). One __syncthreads.
// Then each wave computes out[32, w*64..w*64+64) = Alds[32,512] @ wb^T + bias,
// B-frags loaded directly from wb (512 KB, L2-resident on every XCD).
// grid: 512 blocks. LDS 32 KiB -> 2 blocks/CU, launch_bounds(512,4) -> 128 VGPR.
// ---------------------------------------------------------------------------
__global__ __launch_bounds__(512, 4) void scan_mm(
        const float* __restrict__ q, const float* __restrict__ k,
        const float* __restrict__ v,
        const __hip_bfloat16* __restrict__ wb,
        const float* __restrict__ ksumT, const float* __restrict__ vsumT,
        const float* __restrict__ bias, float* __restrict__ out) {
    __shared__ short Alds[CHUNK * D];   // 32 KiB: attn tile, swizzled colgrps
    const int tid = threadIdx.x;
    const int w = tid >> 6;             // wave = head 0..7
    const int lane = tid & 63;          // dim e within the head
    const int blk = blockIdx.x;         // 0..511
    const int b_ = blk >> 7;            // batch
    const int ch = blk & 127;           // chunk index within (b,h)
    const int n0 = ch * CHUNK;          // first position
    const int bh = b_ * 8 + w;

    // ---- scan phase (proven R3/R6 math) ----
    {
        size_t gbase = ((size_t)bh * N + n0) * E + lane;
        const float* qp = q + gbase;
        const float* kp = k + gbase;
        const float* vp = v + gbase;
        float koff = ksumT[(size_t)(bh * E + lane) * NCH + ch];
        float voff = vsumT[(size_t)(bh * E + lane) * NCH + ch];
        float kc = 0.f, vc = 0.f;
        const int eg = lane >> 3, el = lane & 7;
        #pragma unroll
        for (int g = 0; g < 4; g++) {
            float kb[8], qb[8], vb[8], pr[8], sv[8];
            #pragma unroll
            for (int j = 0; j < 8; j++) {
                size_t o = (size_t)(g * 8 + j) * E;
                kb[j] = kp[o]; qb[j] = qp[o]; vb[j] = vp[o];
            }
            #pragma unroll
            for (int j = 0; j < 8; j++) {
                kc += phi(kb[j]);
                vc += vb[j];
                pr[j] = phi(qb[j]) * (koff + kc);
                sv[j] = voff + vc;
            }
            #pragma unroll
            for (int m = 1; m < 64; m <<= 1) {
                #pragma unroll
                for (int j = 0; j < 8; j++) pr[j] += __shfl_xor(pr[j], m, 64);
            }
            #pragma unroll
            for (int j = 0; j < 8; j++) {
                float s = pr[j];
                __hip_bfloat16 val = __float2bfloat16(s / (s + EPS) * sv[j]);
                int p = g * 8 + j;
                // dim c = w*64 + lane; global colgrp = w*8+eg; swizzle ^ (p&7)
                Alds[p * D + ((((w * 8 + eg) ^ (p & 7)) << 3) | el)] =
                    *reinterpret_cast<short*>(&val);
            }
        }
    }
    __syncthreads();

    // ---- MFMA phase: wave w -> out cols [w*64, w*64+64) ----
    const int lo = lane & 15, quad = lane >> 4;
    floatx4 acc[2][4] = {};
    const short* Bg = (const short*)wb;
    #pragma unroll 2
    for (int kt = 0; kt < 16; kt++) {
        short8 af[2], bfr[4];
        #pragma unroll
        for (int i = 0; i < 2; i++) {
            int ra = i * 16 + lo;
            af[i] = *(const short8*)&Alds[ra * D + (((((kt << 2) | quad)) ^ (ra & 7)) << 3)];
        }
        #pragma unroll
        for (int j = 0; j < 4; j++) {
            int n = w * 64 + j * 16 + lo;
            bfr[j] = *(const short8*)(Bg + (size_t)n * D + (kt << 5) + (quad << 3));
        }
        #pragma unroll
        for (int i = 0; i < 2; i++)
            #pragma unroll
            for (int j = 0; j < 4; j++)
                acc[i][j] = __builtin_amdgcn_mfma_f32_16x16x32_bf16(af[i], bfr[j], acc[i][j], 0, 0, 0);
    }

    // ---- epilogue ----
    #pragma unroll
    for (int i = 0; i < 2; i++) {
        #pragma unroll
        for (int j = 0; j < 4; j++) {
            int n = w * 64 + j * 16 + lo;
            float bv = bias[n];
            #pragma unroll
            for (int r = 0; r < 4; r++) {
                int m = i * 16 + quad * 4 + r;   // position within the 32
                out[((size_t)b_ * N + n0 + m) * D + n] = acc[i][j][r] + bv;
            }
        }
    }
}

// ---------------------------------------------------------------------------

extern "C" void kernel_launch(void* const* d_in, const int* in_sizes, int n_in,
                              void* d_out, int out_size, void* d_ws, size_t ws_size,
                              hipStream_t stream) {
    const float* q   = (const float*)d_in[0];
    const float* k   = (const float*)d_in[1];
    const float* v   = (const float*)d_in[2];
    // d_in[3] = mask (unused)
    const float* W   = (const float*)d_in[4];
    const float* bfc = (const float*)d_in[5];
    float* out = (float*)d_out;

    char* ws = (char*)d_ws;
    __hip_bfloat16* wb = (__hip_bfloat16*)ws;                 // 512 KiB
    float* ksumT = (float*)(ws + (512 << 10));                // 1 MiB
    float* vsumT = ksumT + BH * NCH * E;                      // 1 MiB

    hipLaunchKernelGGL(chunk_sums, dim3(BH * NCH / 4), dim3(256), 0, stream,
                       k, v, W, wb, ksumT, vsumT);
    hipLaunchKernelGGL(chunk_prefix, dim3(BH * E / 4), dim3(256), 0, stream, ksumT, vsumT);
    hipLaunchKernelGGL(scan_mm, dim3(B * NCH), dim3(512), 0, stream,
                       q, k, v, wb, ksumT, vsumT, bfc, out);
}